// Round 9
// baseline (33.500 us; speedup 1.0000x reference)
//
#include <hip/hip_runtime.h>
#include <cmath>

#define BB 64
#define HH 64
#define WW 64
#define CI 16
#define CO 32
#define NIN 144           // 3*3*16 = 9 * 16 -> nine 32x32x16 MFMA k-steps, no padding

typedef __attribute__((ext_vector_type(8)))  short s16x8;   // 8 bf16 (4 VGPRs)
typedef __attribute__((ext_vector_type(16))) float f32x16;  // 32x32 accumulator

// RNE pack of two fp32 -> (lo, hi) bf16 in one u32
__device__ __forceinline__ unsigned pk_bf16(float a, float b) {
    unsigned ua = __float_as_uint(a);
    unsigned ub = __float_as_uint(b);
    ua = (ua + 0x7fffu + ((ua >> 16) & 1u)) >> 16;
    ub = (ub + 0x7fffu + ((ub >> 16) & 1u)) & 0xffff0000u;
    return ua | ub;
}

// ---------------------------------------------------------------------------
// DIAGNOSTIC ROUND: identical compute structure to round 8, but launched with
// a 2x grid (blocks 2048..4095 duplicate 0..2047, writing byte-identical
// values). The single ~45us dispatch cracks the rocprof top-5 so we finally
// get real counters (VALUBusy / MfmaUtil / FETCH / WRITE / LDS conflicts /
// VGPR) for this kernel shape. All traffic scales uniformly 2x.
// ---------------------------------------------------------------------------
__global__ __launch_bounds__(256, 5) void hyp_fused(
        const float* __restrict__ x,
        const float* __restrict__ z,
        const float* __restrict__ r,
        float* __restrict__ out,
        float ratio, float ratio2) {
    __shared__ __align__(16) unsigned short xs[2][4][66][8]; // bf16 x slab [ci-half][row][col]
    __shared__ __align__(16) unsigned zf[9][64][4];          // A-fragments (bf16 pairs)
    __shared__ float  qs[4][66];                             // per-cell sum x^2
    __shared__ float  tpart[8][32];                          // ||z||^2 partials
    __shared__ float2 lam2[128];                             // {lam*proj_scale, lam-1}
    __shared__ __align__(16) float pre4[32][4];              // {cosh/zn, sinh, 2zn, -}

    const int tid  = threadIdx.x;
    const int lane = tid & 63;
    const int wv   = tid >> 6;

    // duplicate-half mapping (diagnostic): blocks >= 2048 redo block-2048's work
    const int bid = blockIdx.x & 2047;
    // XCD-chunked bijective swizzle (2048 = 8 * 256): XCD i owns 8 whole images
    const int lid = ((bid & 7) << 8) | (bid >> 3);
    const int b   = lid >> 5;
    const int h   = (lid & 31) << 1;          // row pair {h, h+1}

    // early r prefetch (used by table phase after barrier)
    float rv = 0.f;
    if (tid < 32) rv = r[tid];

    const float* xb = x + (b << 16);          // image base (64*64*16 floats)

    // ---- stage x slab: rows h-1..h+2, cols -1..64 (edge-clamped) ----
    for (int cell = tid; cell < 4 * 66; cell += 256) {
        int rr = cell / 66;
        int wi = cell - rr * 66;
        int gh = h - 1 + rr; gh = gh < 0 ? 0 : (gh > HH - 1 ? HH - 1 : gh);
        int gw = wi - 1;     gw = gw < 0 ? 0 : gw;
        gw = gw > WW - 1 ? WW - 1 : gw;
        const float4* src = (const float4*)(xb + ((gh << 6) + gw) * CI);
        float4 v0 = src[0], v1 = src[1], v2 = src[2], v3 = src[3];
        float q = 0.f;
        q = fmaf(v0.x, v0.x, q); q = fmaf(v0.y, v0.y, q);
        q = fmaf(v0.z, v0.z, q); q = fmaf(v0.w, v0.w, q);
        q = fmaf(v1.x, v1.x, q); q = fmaf(v1.y, v1.y, q);
        q = fmaf(v1.z, v1.z, q); q = fmaf(v1.w, v1.w, q);
        q = fmaf(v2.x, v2.x, q); q = fmaf(v2.y, v2.y, q);
        q = fmaf(v2.z, v2.z, q); q = fmaf(v2.w, v2.w, q);
        q = fmaf(v3.x, v3.x, q); q = fmaf(v3.y, v3.y, q);
        q = fmaf(v3.z, v3.z, q); q = fmaf(v3.w, v3.w, q);
        uint4 lo, hi4;
        lo.x  = pk_bf16(v0.x, v0.y);  lo.y  = pk_bf16(v0.z, v0.w);
        lo.z  = pk_bf16(v1.x, v1.y);  lo.w  = pk_bf16(v1.z, v1.w);
        hi4.x = pk_bf16(v2.x, v2.y);  hi4.y = pk_bf16(v2.z, v2.w);
        hi4.z = pk_bf16(v3.x, v3.y);  hi4.w = pk_bf16(v3.z, v3.w);
        *(uint4*)&xs[0][rr][wi][0] = lo;
        *(uint4*)&xs[1][rr][wi][0] = hi4;
        qs[rr][wi] = q;
    }

    // ---- stage z as A-fragments + in-register ||z||^2 partials ----
    {
        int ch = tid & 31;
        int p0 = tid >> 5;                    // 0..7
        float sq = 0.f;
#pragma unroll
        for (int rep = 0; rep < 9; ++rep) {
            int k2 = rep * 8 + p0;            // pair index, k = 2*k2
            float z0 = z[(k2 << 6) + ch];
            float z1 = z[(k2 << 6) + 32 + ch];
            sq = fmaf(z0, z0, fmaf(z1, z1, sq));
            int s  = k2 >> 3;
            int hi = (k2 >> 2) & 1;
            int j2 = k2 & 3;
            zf[s][ch | (hi << 5)][j2] = pk_bf16(ratio * z0, ratio * z1);
        }
        tpart[p0][ch] = sq;
    }
    __syncthreads();

    // ---- per-pixel lambda (128 pixels) ----
    if (tid < 128) {
        int rr = tid >> 6, c = tid & 63;
        float s2 = 0.f;
#pragma unroll
        for (int kh = 0; kh < 3; ++kh)
#pragma unroll
            for (int kw = 0; kw < 3; ++kw)
                s2 += qs[rr + kh][c + kw];
        s2 *= ratio2;
        float yn = sqrtf(s2);
        float se = 1.0f;
        const float mn = 0.99999f;            // (1-1e-5)/sqrt(c)
        if (yn > mn) se = mn / fmaxf(yn, 1e-7f);
        float yn2 = s2 * se * se;
        float lam = 2.0f * __builtin_amdgcn_rcpf(fmaxf(1.0f - yn2, 1e-7f));
        lam2[tid] = make_float2(lam * se, lam - 1.0f);
    }
    // ---- per-channel tables (overlaps with MFMA phase of other threads) ----
    if (tid < 32) {
        float s = tpart[0][tid];
#pragma unroll
        for (int p = 1; p < 8; ++p) s += tpart[p][tid];
        float zn = fmaxf(sqrtf(s), 1e-7f);    // fp32-exact ||z||
        float tc = 2.0f * rv;
        pre4[tid][0] = coshf(tc) / zn;
        pre4[tid][1] = sinhf(tc);
        pre4[tid][2] = 2.0f * zn;
    }

    // ---- MFMA: 9 k-steps of 32x32x16 ----
    const int px    = lane & 31;              // pixel within 32-tile
    const int hi    = lane >> 5;              // k-half / ci-half selector
    const int rloc  = wv >> 1;                // local output row (0/1)
    const int cbase = (wv & 1) << 5;          // pixel-column base (0/32)

    f32x16 acc = {};
#pragma unroll
    for (int s = 0; s < 9; ++s) {
        const int kh = s / 3, kw = s % 3;     // compile-time (full unroll)
        s16x8 afrag = *(const s16x8*)&zf[s][lane][0];
        s16x8 bfrag = *(const s16x8*)&xs[hi][rloc + kh][cbase + px + kw][0];
        acc = __builtin_amdgcn_mfma_f32_32x32x16_bf16(afrag, bfrag, acc, 0, 0, 0);
    }
    __syncthreads();                          // lam2 + pre4 now visible

    // ---- epilogue: 16 channels in-register, one pixel per lane ----
    float2 lm2 = lam2[(rloc << 6) + cbase + px];
    const float ls = lm2.x, lm = lm2.y;
    float wn2 = 0.f;
#pragma unroll
    for (int reg = 0; reg < 16; ++reg) {
        const int m = (reg & 3) + ((reg >> 2) << 3) + (hi << 2);  // channel
        float4 t4 = *(const float4*)&pre4[m][0];
        float arg = fmaf(ls * acc[reg], t4.x, -(lm * t4.y));
        float ax  = fabsf(arg);
        float v = copysignf(t4.z * __logf(ax + __builtin_amdgcn_sqrtf(fmaf(ax, ax, 1.f))), arg);
        float u = v * 0.02f;                  // v/50
        float qq = u * u;
        float t = v * fmaf(qq, fmaf(qq, 0.1333333f, -0.3333333f), 1.0f); // 50*tanh(v/50)
        float e = __expf(t);
        float w = 0.5f * (e - __builtin_amdgcn_rcpf(e));                 // sinh(t)
        acc[reg] = w;                         // reuse accumulator registers
        wn2 = fmaf(w, w, wn2);
    }
    wn2 += __shfl_xor(wn2, 32);               // partner lane has other 16 channels
    float inv = __builtin_amdgcn_rcpf(1.f + __builtin_amdgcn_sqrtf(1.f + wn2));

    float* op = out + ((((b << 6) + h + rloc) << 6) + cbase + px) * CO + (hi << 2);
#pragma unroll
    for (int q = 0; q < 4; ++q) {             // channels {8q+4hi .. +3}
        float4 o;
        o.x = acc[q * 4 + 0] * inv;
        o.y = acc[q * 4 + 1] * inv;
        o.z = acc[q * 4 + 2] * inv;
        o.w = acc[q * 4 + 3] * inv;
        *(float4*)(op + (q << 3)) = o;
    }
}

// ---------------------------------------------------------------------------
extern "C" void kernel_launch(void* const* d_in, const int* in_sizes, int n_in,
                              void* d_out, int out_size, void* d_ws, size_t ws_size,
                              hipStream_t stream) {
    const float* x = (const float*)d_in[0];
    const float* z = (const float*)d_in[1];
    const float* r = (const float*)d_in[2];
    float* out = (float*)d_out;

    double lb_n = lgamma(NIN / 2.0) + lgamma(0.5) - lgamma((NIN + 1) / 2.0);
    double lb_c = lgamma(CI  / 2.0) + lgamma(0.5) - lgamma((CI  + 1) / 2.0);
    float ratio = (float)exp(lb_n - lb_c);

    // DIAGNOSTIC: 2x grid, second half duplicates first (byte-identical writes)
    hyp_fused<<<BB * HH, 256, 0, stream>>>(x, z, r, out, ratio, ratio * ratio);
}

// Round 11
// 20.438 us; speedup vs baseline: 1.6391x; 1.6391x over previous
//
#include <hip/hip_runtime.h>
#include <hip/hip_bf16.h>
#include <cmath>
#include <cstring>

#define BB 64
#define HH 64
#define WW 64
#define CI 16
#define CO 32
#define NIN 144           // 3*3*16 = 9 * 16 -> nine 32x32x16 MFMA k-steps

typedef __attribute__((ext_vector_type(8)))  short s16x8;   // 8 bf16 (4 VGPRs)
typedef __attribute__((ext_vector_type(16))) float f32x16;  // 32x32 accumulator

// HW packed fp32x2 -> bf16x2 (v_cvt_pk_bf16_f32, RNE), low = a
__device__ __forceinline__ unsigned pk2(float a, float b) {
    __hip_bfloat162 h = __float22bfloat162_rn(make_float2(a, b));
    unsigned u;
    memcpy(&u, &h, sizeof(u));
    return u;
}

// ---------------------------------------------------------------------------
// Single fused kernel. One block = (b, rows {h..h+3}, 64 cols) = 256 pixels,
// grid 1024. 4 waves, each wave computes TWO 32ch x 32px tiles (rows rloc and
// rloc+2) sharing the A-fragment reads. z-staging and halo amortized 2x vs
// the 2-row version. mfma_f32_32x32x16_bf16, A = ratio*z^T, B = patches.
// C-layout: pixel = lane&31, 16 channels in-register -> wn2 = 15 adds + one
// shfl_xor(32).
// ---------------------------------------------------------------------------
__global__ __launch_bounds__(256, 4) void hyp_fused(
        const float* __restrict__ x,
        const float* __restrict__ z,
        const float* __restrict__ r,
        float* __restrict__ out,
        float ratio, float ratio2) {
    __shared__ __align__(16) unsigned short xs[2][6][66][8]; // bf16 x slab
    __shared__ __align__(16) unsigned zf[9][64][4];          // A-fragments
    __shared__ float  qs[6][66];                             // per-cell sum x^2
    __shared__ float  tpart[8][32];                          // ||z||^2 partials
    __shared__ float2 lam2[256];                             // {lam*scale, lam-1}
    __shared__ __align__(16) float pre4[32][4];              // {cosh/zn, sinh, 2zn*ln2, -}

    const int tid  = threadIdx.x;
    const int lane = tid & 63;
    const int wv   = tid >> 6;

    // XCD-chunked bijective swizzle (1024 = 8 * 128)
    const int bid = blockIdx.x;
    const int lid = ((bid & 7) << 7) | (bid >> 3);
    const int b   = lid >> 4;
    const int h   = (lid & 15) << 2;          // row quad {h..h+3}

    float rv = 0.f;
    if (tid < 32) rv = r[tid];

    const float* xb = x + (b << 16);          // image base

    // ---- stage x slab: rows h-1..h+4, cols -1..64 (edge-clamped) ----
    for (int cell = tid; cell < 6 * 66; cell += 256) {
        int rr = cell / 66;
        int wi = cell - rr * 66;
        int gh = h - 1 + rr; gh = gh < 0 ? 0 : (gh > HH - 1 ? HH - 1 : gh);
        int gw = wi - 1;     gw = gw < 0 ? 0 : (gw > WW - 1 ? WW - 1 : gw);
        const float4* src = (const float4*)(xb + ((gh << 6) + gw) * CI);
        float4 v0 = src[0], v1 = src[1], v2 = src[2], v3 = src[3];
        float q = 0.f;
        q = fmaf(v0.x, v0.x, q); q = fmaf(v0.y, v0.y, q);
        q = fmaf(v0.z, v0.z, q); q = fmaf(v0.w, v0.w, q);
        q = fmaf(v1.x, v1.x, q); q = fmaf(v1.y, v1.y, q);
        q = fmaf(v1.z, v1.z, q); q = fmaf(v1.w, v1.w, q);
        q = fmaf(v2.x, v2.x, q); q = fmaf(v2.y, v2.y, q);
        q = fmaf(v2.z, v2.z, q); q = fmaf(v2.w, v2.w, q);
        q = fmaf(v3.x, v3.x, q); q = fmaf(v3.y, v3.y, q);
        q = fmaf(v3.z, v3.z, q); q = fmaf(v3.w, v3.w, q);
        uint4 lo, hi4;
        lo.x  = pk2(v0.x, v0.y);  lo.y  = pk2(v0.z, v0.w);
        lo.z  = pk2(v1.x, v1.y);  lo.w  = pk2(v1.z, v1.w);
        hi4.x = pk2(v2.x, v2.y);  hi4.y = pk2(v2.z, v2.w);
        hi4.z = pk2(v3.x, v3.y);  hi4.w = pk2(v3.z, v3.w);
        *(uint4*)&xs[0][rr][wi][0] = lo;
        *(uint4*)&xs[1][rr][wi][0] = hi4;
        qs[rr][wi] = q;
    }

    // ---- stage z as A-fragments + in-register ||z||^2 partials ----
    {
        int ch = tid & 31;
        int p0 = tid >> 5;                    // 0..7
        float sq = 0.f;
#pragma unroll
        for (int rep = 0; rep < 9; ++rep) {
            int k2 = rep * 8 + p0;            // pair index, k = 2*k2
            float z0 = z[(k2 << 6) + ch];
            float z1 = z[(k2 << 6) + 32 + ch];
            sq = fmaf(z0, z0, fmaf(z1, z1, sq));
            int s  = k2 >> 3;
            int hi = (k2 >> 2) & 1;
            int j2 = k2 & 3;
            zf[s][ch | (hi << 5)][j2] = pk2(ratio * z0, ratio * z1);
        }
        tpart[p0][ch] = sq;
    }
    __syncthreads();

    // ---- per-pixel lambda (256 pixels, all threads, no divergence) ----
    {
        int rr = tid >> 6, c = tid & 63;
        float s2 = 0.f;
#pragma unroll
        for (int kh = 0; kh < 3; ++kh)
#pragma unroll
            for (int kw = 0; kw < 3; ++kw)
                s2 += qs[rr + kh][c + kw];
        s2 *= ratio2;
        float yn = sqrtf(s2);
        float se = 1.0f;
        const float mn = 0.99999f;            // (1-1e-5)/sqrt(c)
        if (yn > mn) se = mn / fmaxf(yn, 1e-7f);
        float yn2 = s2 * se * se;
        float lam = 2.0f * __builtin_amdgcn_rcpf(fmaxf(1.0f - yn2, 1e-7f));
        lam2[tid] = make_float2(lam * se, lam - 1.0f);
    }
    // ---- per-channel tables (overlaps with MFMA phase) ----
    if (tid < 32) {
        float s = tpart[0][tid];
#pragma unroll
        for (int p = 1; p < 8; ++p) s += tpart[p][tid];
        float zn = fmaxf(sqrtf(s), 1e-7f);
        float tc = 2.0f * rv;
        pre4[tid][0] = coshf(tc) / zn;
        pre4[tid][1] = sinhf(tc);
        pre4[tid][2] = 2.0f * zn * 0.69314718f;   // fold ln2 for __log2f
    }

    // ---- MFMA: 9 k-steps, two 32x32 tiles per wave (rows rloc, rloc+2) ----
    const int px    = lane & 31;
    const int hi    = lane >> 5;              // k-half / ci-half selector
    const int rloc  = wv >> 1;                // 0/1
    const int cb    = (wv & 1) << 5;          // pixel-column base

    f32x16 accA = {}, accB = {};
#pragma unroll
    for (int s = 0; s < 9; ++s) {
        const int kh = s / 3, kw = s % 3;     // compile-time
        s16x8 afrag = *(const s16x8*)&zf[s][lane][0];
        s16x8 bfA = *(const s16x8*)&xs[hi][rloc + kh][cb + px + kw][0];
        s16x8 bfB = *(const s16x8*)&xs[hi][rloc + 2 + kh][cb + px + kw][0];
        accA = __builtin_amdgcn_mfma_f32_32x32x16_bf16(afrag, bfA, accA, 0, 0, 0);
        accB = __builtin_amdgcn_mfma_f32_32x32x16_bf16(afrag, bfB, accB, 0, 0, 0);
    }
    __syncthreads();                          // lam2 + pre4 visible

    // ---- epilogue: both tiles per reg so pre4 reads are shared ----
    float2 lA = lam2[(rloc << 6) + cb + px];
    float2 lB = lam2[((rloc + 2) << 6) + cb + px];
    float wn2A = 0.f, wn2B = 0.f;
#pragma unroll
    for (int reg = 0; reg < 16; ++reg) {
        const int m = (reg & 3) + ((reg >> 2) << 3) + (hi << 2);
        float4 t4 = *(const float4*)&pre4[m][0];
        // tile A
        {
            float arg = fmaf(lA.x * accA[reg], t4.x, -(lA.y * t4.y));
            float ax  = fabsf(arg);
            float v = copysignf(t4.z * __log2f(ax + __builtin_amdgcn_sqrtf(fmaf(ax, ax, 1.f))), arg);
            float u = v * 0.02f;
            float qq = u * u;
            float t = v * fmaf(qq, fmaf(qq, 0.1333333f, -0.3333333f), 1.0f);
            float e = __expf(t);
            float w = 0.5f * (e - __builtin_amdgcn_rcpf(e));
            accA[reg] = w;
            wn2A = fmaf(w, w, wn2A);
        }
        // tile B
        {
            float arg = fmaf(lB.x * accB[reg], t4.x, -(lB.y * t4.y));
            float ax  = fabsf(arg);
            float v = copysignf(t4.z * __log2f(ax + __builtin_amdgcn_sqrtf(fmaf(ax, ax, 1.f))), arg);
            float u = v * 0.02f;
            float qq = u * u;
            float t = v * fmaf(qq, fmaf(qq, 0.1333333f, -0.3333333f), 1.0f);
            float e = __expf(t);
            float w = 0.5f * (e - __builtin_amdgcn_rcpf(e));
            accB[reg] = w;
            wn2B = fmaf(w, w, wn2B);
        }
    }
    wn2A += __shfl_xor(wn2A, 32);
    wn2B += __shfl_xor(wn2B, 32);
    float invA = __builtin_amdgcn_rcpf(1.f + __builtin_amdgcn_sqrtf(1.f + wn2A));
    float invB = __builtin_amdgcn_rcpf(1.f + __builtin_amdgcn_sqrtf(1.f + wn2B));

    float* opA = out + ((((b << 6) + h + rloc)     << 6) + cb + px) * CO + (hi << 2);
    float* opB = out + ((((b << 6) + h + rloc + 2) << 6) + cb + px) * CO + (hi << 2);
#pragma unroll
    for (int q = 0; q < 4; ++q) {
        float4 oA, oB;
        oA.x = accA[q * 4 + 0] * invA; oA.y = accA[q * 4 + 1] * invA;
        oA.z = accA[q * 4 + 2] * invA; oA.w = accA[q * 4 + 3] * invA;
        oB.x = accB[q * 4 + 0] * invB; oB.y = accB[q * 4 + 1] * invB;
        oB.z = accB[q * 4 + 2] * invB; oB.w = accB[q * 4 + 3] * invB;
        *(float4*)(opA + (q << 3)) = oA;
        *(float4*)(opB + (q << 3)) = oB;
    }
}

// ---------------------------------------------------------------------------
extern "C" void kernel_launch(void* const* d_in, const int* in_sizes, int n_in,
                              void* d_out, int out_size, void* d_ws, size_t ws_size,
                              hipStream_t stream) {
    const float* x = (const float*)d_in[0];
    const float* z = (const float*)d_in[1];
    const float* r = (const float*)d_in[2];
    float* out = (float*)d_out;

    double lb_n = lgamma(NIN / 2.0) + lgamma(0.5) - lgamma((NIN + 1) / 2.0);
    double lb_c = lgamma(CI  / 2.0) + lgamma(0.5) - lgamma((CI  + 1) / 2.0);
    float ratio = (float)exp(lb_n - lb_c);

    hyp_fused<<<BB * HH / 4, 256, 0, stream>>>(x, z, r, out, ratio, ratio * ratio);
}

// Round 12
// 20.372 us; speedup vs baseline: 1.6444x; 1.0032x over previous
//
#include <hip/hip_runtime.h>
#include <hip/hip_bf16.h>
#include <cmath>
#include <cstring>

#define BB 64
#define HH 64
#define WW 64
#define CI 16
#define CO 32
#define NIN 144           // 3*3*16 = 9 * 16 -> nine 32x32x16 MFMA k-steps

typedef __attribute__((ext_vector_type(8)))  short s16x8;   // 8 bf16 (4 VGPRs)
typedef __attribute__((ext_vector_type(16))) float f32x16;  // 32x32 accumulator

// HW packed fp32x2 -> bf16x2 (v_cvt_pk_bf16_f32, RNE), low = a
__device__ __forceinline__ unsigned pk2(float a, float b) {
    __hip_bfloat162 h = __float22bfloat162_rn(make_float2(a, b));
    unsigned u;
    memcpy(&u, &h, sizeof(u));
    return u;
}

// ---------------------------------------------------------------------------
// Single fused kernel. One block = (b, rows {h..h+7}, 64 cols) = 512 pixels,
// 512 threads (8 waves), grid 512. Each wave computes TWO 32ch x 32px tiles
// (rows rloc and rloc+4) sharing A-fragment reads. Per-thread z-staging is
// halved vs the 4-row version (4.5 pair-loads) and x halo amplification drops
// to 1.25x. mfma_f32_32x32x16_bf16, A = ratio*z^T, B = patches.
// C-layout: pixel = lane&31, 16 channels in-register -> wn2 = 15 adds + one
// shfl_xor(32).
// ---------------------------------------------------------------------------
__global__ __launch_bounds__(512, 4) void hyp_fused(
        const float* __restrict__ x,
        const float* __restrict__ z,
        const float* __restrict__ r,
        float* __restrict__ out,
        float ratio, float ratio2) {
    __shared__ __align__(16) unsigned short xs[2][10][66][8]; // bf16 x slab
    __shared__ __align__(16) unsigned zf[9][64][4];           // A-fragments
    __shared__ float  qs[10][66];                             // per-cell sum x^2
    __shared__ float  tpart[16][32];                          // ||z||^2 partials
    __shared__ float2 lam2[512];                              // {lam*scale, lam-1}
    __shared__ __align__(16) float pre4[32][4];               // {cosh/zn, sinh, 2zn*ln2, -}

    const int tid  = threadIdx.x;
    const int lane = tid & 63;
    const int wv   = tid >> 6;                // 0..7

    // XCD-chunked bijective swizzle (512 = 8 * 64)
    const int bid = blockIdx.x;
    const int lid = ((bid & 7) << 6) | (bid >> 3);
    const int b   = lid >> 3;
    const int h   = (lid & 7) << 3;           // row octet {h..h+7}

    float rv = 0.f;
    if (tid < 32) rv = r[tid];

    const float* xb = x + (b << 16);          // image base

    // ---- stage x slab: rows h-1..h+8, cols -1..64 (edge-clamped) ----
    for (int cell = tid; cell < 10 * 66; cell += 512) {
        int rr = cell / 66;
        int wi = cell - rr * 66;
        int gh = h - 1 + rr; gh = gh < 0 ? 0 : (gh > HH - 1 ? HH - 1 : gh);
        int gw = wi - 1;     gw = gw < 0 ? 0 : (gw > WW - 1 ? WW - 1 : gw);
        const float4* src = (const float4*)(xb + ((gh << 6) + gw) * CI);
        float4 v0 = src[0], v1 = src[1], v2 = src[2], v3 = src[3];
        float q = 0.f;
        q = fmaf(v0.x, v0.x, q); q = fmaf(v0.y, v0.y, q);
        q = fmaf(v0.z, v0.z, q); q = fmaf(v0.w, v0.w, q);
        q = fmaf(v1.x, v1.x, q); q = fmaf(v1.y, v1.y, q);
        q = fmaf(v1.z, v1.z, q); q = fmaf(v1.w, v1.w, q);
        q = fmaf(v2.x, v2.x, q); q = fmaf(v2.y, v2.y, q);
        q = fmaf(v2.z, v2.z, q); q = fmaf(v2.w, v2.w, q);
        q = fmaf(v3.x, v3.x, q); q = fmaf(v3.y, v3.y, q);
        q = fmaf(v3.z, v3.z, q); q = fmaf(v3.w, v3.w, q);
        uint4 lo, hi4;
        lo.x  = pk2(v0.x, v0.y);  lo.y  = pk2(v0.z, v0.w);
        lo.z  = pk2(v1.x, v1.y);  lo.w  = pk2(v1.z, v1.w);
        hi4.x = pk2(v2.x, v2.y);  hi4.y = pk2(v2.z, v2.w);
        hi4.z = pk2(v3.x, v3.y);  hi4.w = pk2(v3.z, v3.w);
        *(uint4*)&xs[0][rr][wi][0] = lo;
        *(uint4*)&xs[1][rr][wi][0] = hi4;
        qs[rr][wi] = q;
    }

    // ---- stage z as A-fragments (512 threads -> 4.5 pairs each) ----
    {
        int ch = tid & 31;
        int p0 = tid >> 5;                    // 0..15
        float sq = 0.f;
#pragma unroll
        for (int rep = 0; rep < 5; ++rep) {
            int k2 = rep * 16 + p0;           // pair index, k = 2*k2
            if (k2 < 72) {
                float z0 = z[(k2 << 6) + ch];
                float z1 = z[(k2 << 6) + 32 + ch];
                sq = fmaf(z0, z0, fmaf(z1, z1, sq));
                int s  = k2 >> 3;
                int hi = (k2 >> 2) & 1;
                int j2 = k2 & 3;
                zf[s][ch | (hi << 5)][j2] = pk2(ratio * z0, ratio * z1);
            }
        }
        tpart[p0][ch] = sq;
    }
    __syncthreads();

    // ---- per-pixel lambda (512 pixels, all threads) ----
    {
        int rr = tid >> 6, c = tid & 63;
        float s2 = 0.f;
#pragma unroll
        for (int kh = 0; kh < 3; ++kh)
#pragma unroll
            for (int kw = 0; kw < 3; ++kw)
                s2 += qs[rr + kh][c + kw];
        s2 *= ratio2;
        float yn = sqrtf(s2);
        float se = 1.0f;
        const float mn = 0.99999f;            // (1-1e-5)/sqrt(c)
        if (yn > mn) se = mn / fmaxf(yn, 1e-7f);
        float yn2 = s2 * se * se;
        float lam = 2.0f * __builtin_amdgcn_rcpf(fmaxf(1.0f - yn2, 1e-7f));
        lam2[tid] = make_float2(lam * se, lam - 1.0f);
    }
    // ---- per-channel tables (overlaps with MFMA phase) ----
    if (tid < 32) {
        float s = tpart[0][tid];
#pragma unroll
        for (int p = 1; p < 16; ++p) s += tpart[p][tid];
        float zn = fmaxf(sqrtf(s), 1e-7f);
        float tc = 2.0f * rv;
        pre4[tid][0] = coshf(tc) / zn;
        pre4[tid][1] = sinhf(tc);
        pre4[tid][2] = 2.0f * zn * 0.69314718f;   // fold ln2 for __log2f
    }

    // ---- MFMA: 9 k-steps, two 32x32 tiles per wave (rows rloc, rloc+4) ----
    const int px    = lane & 31;
    const int hi    = lane >> 5;              // k-half / ci-half selector
    const int rloc  = wv >> 1;                // 0..3
    const int cb    = (wv & 1) << 5;          // pixel-column base

    f32x16 accA = {}, accB = {};
#pragma unroll
    for (int s = 0; s < 9; ++s) {
        const int kh = s / 3, kw = s % 3;     // compile-time
        s16x8 afrag = *(const s16x8*)&zf[s][lane][0];
        s16x8 bfA = *(const s16x8*)&xs[hi][rloc + kh][cb + px + kw][0];
        s16x8 bfB = *(const s16x8*)&xs[hi][rloc + 4 + kh][cb + px + kw][0];
        accA = __builtin_amdgcn_mfma_f32_32x32x16_bf16(afrag, bfA, accA, 0, 0, 0);
        accB = __builtin_amdgcn_mfma_f32_32x32x16_bf16(afrag, bfB, accB, 0, 0, 0);
    }
    __syncthreads();                          // lam2 + pre4 visible

    // ---- epilogue: both tiles per reg so pre4 reads are shared ----
    float2 lA = lam2[(rloc << 6) + cb + px];
    float2 lB = lam2[((rloc + 4) << 6) + cb + px];
    float wn2A = 0.f, wn2B = 0.f;
#pragma unroll
    for (int reg = 0; reg < 16; ++reg) {
        const int m = (reg & 3) + ((reg >> 2) << 3) + (hi << 2);
        float4 t4 = *(const float4*)&pre4[m][0];
        // tile A
        {
            float arg = fmaf(lA.x * accA[reg], t4.x, -(lA.y * t4.y));
            float ax  = fabsf(arg);
            float v = copysignf(t4.z * __log2f(ax + __builtin_amdgcn_sqrtf(fmaf(ax, ax, 1.f))), arg);
            float u = v * 0.02f;
            float qq = u * u;
            float t = v * fmaf(qq, fmaf(qq, 0.1333333f, -0.3333333f), 1.0f);
            float e = __expf(t);
            float w = 0.5f * (e - __builtin_amdgcn_rcpf(e));
            accA[reg] = w;
            wn2A = fmaf(w, w, wn2A);
        }
        // tile B
        {
            float arg = fmaf(lB.x * accB[reg], t4.x, -(lB.y * t4.y));
            float ax  = fabsf(arg);
            float v = copysignf(t4.z * __log2f(ax + __builtin_amdgcn_sqrtf(fmaf(ax, ax, 1.f))), arg);
            float u = v * 0.02f;
            float qq = u * u;
            float t = v * fmaf(qq, fmaf(qq, 0.1333333f, -0.3333333f), 1.0f);
            float e = __expf(t);
            float w = 0.5f * (e - __builtin_amdgcn_rcpf(e));
            accB[reg] = w;
            wn2B = fmaf(w, w, wn2B);
        }
    }
    wn2A += __shfl_xor(wn2A, 32);
    wn2B += __shfl_xor(wn2B, 32);
    float invA = __builtin_amdgcn_rcpf(1.f + __builtin_amdgcn_sqrtf(1.f + wn2A));
    float invB = __builtin_amdgcn_rcpf(1.f + __builtin_amdgcn_sqrtf(1.f + wn2B));

    float* opA = out + ((((b << 6) + h + rloc)     << 6) + cb + px) * CO + (hi << 2);
    float* opB = out + ((((b << 6) + h + rloc + 4) << 6) + cb + px) * CO + (hi << 2);
#pragma unroll
    for (int q = 0; q < 4; ++q) {
        float4 oA, oB;
        oA.x = accA[q * 4 + 0] * invA; oA.y = accA[q * 4 + 1] * invA;
        oA.z = accA[q * 4 + 2] * invA; oA.w = accA[q * 4 + 3] * invA;
        oB.x = accB[q * 4 + 0] * invB; oB.y = accB[q * 4 + 1] * invB;
        oB.z = accB[q * 4 + 2] * invB; oB.w = accB[q * 4 + 3] * invB;
        *(float4*)(opA + (q << 3)) = oA;
        *(float4*)(opB + (q << 3)) = oB;
    }
}

// ---------------------------------------------------------------------------
extern "C" void kernel_launch(void* const* d_in, const int* in_sizes, int n_in,
                              void* d_out, int out_size, void* d_ws, size_t ws_size,
                              hipStream_t stream) {
    const float* x = (const float*)d_in[0];
    const float* z = (const float*)d_in[1];
    const float* r = (const float*)d_in[2];
    float* out = (float*)d_out;

    double lb_n = lgamma(NIN / 2.0) + lgamma(0.5) - lgamma((NIN + 1) / 2.0);
    double lb_c = lgamma(CI  / 2.0) + lgamma(0.5) - lgamma((CI  + 1) / 2.0);
    float ratio = (float)exp(lb_n - lb_c);

    hyp_fused<<<BB * HH / 8, 512, 0, stream>>>(x, z, r, out, ratio, ratio * ratio);
}